// Round 4
// baseline (388.141 us; speedup 1.0000x reference)
//
#include <hip/hip_runtime.h>

#define BOX 71
#define NF 32
#define MAX_DIST_F 35.0f
#define SLICE_FLOATS (BOX * BOX * BOX * NF)   // 11,453,152 floats = 45.8 MB (batch slice 0)

typedef float vfloat4 __attribute__((ext_vector_type(4)));  // native vector: OK for nontemporal builtin

// K1: zero ONLY batch slice 0 (the atomic-scatter target region). 45.8 MB -> ~8 us.
__global__ __launch_bounds__(256) void MakeGrid_zero_slice0(
    vfloat4* __restrict__ out, int n4)
{
    int stride = gridDim.x * blockDim.x;
    vfloat4 z = {0.f, 0.f, 0.f, 0.f};
    for (int i = blockIdx.x * blockDim.x + threadIdx.x; i < n4; i += stride)
        out[i] = z;
}

// K2 (fused): 1/4 of blocks scatter-add points into slice 0 (atomic-bound, ~0.5 TB/s
// effective); 3/4 of blocks stream-zero slices 1..7 (BW-bound, ~6 TB/s) with
// nontemporal stores to keep L2 clean for the atomics. Disjoint regions -> no sync
// needed; stream order after K1 guarantees slice 0 is zeroed before atomics land.
__global__ __launch_bounds__(256) void MakeGrid_fused_scatter_zero(
    const float* __restrict__ coords,
    const float* __restrict__ features,
    float* __restrict__ grid,          // slice 0 base
    vfloat4* __restrict__ rest,        // slices 1..7 base (16B-aligned)
    size_t rest_n4,
    int total_tasks)                   // total_points * 32
{
    int b = blockIdx.x;
    int tid = threadIdx.x;

    if ((b & 3) == 0) {
        // ---- scatter blocks: blockIdx 0,4,8,... -> sb in [0, gridDim/4) ----
        int sb = b >> 2;
        int stride = (gridDim.x >> 2) * blockDim.x;   // 2048*256 = 524288
        for (int t = sb * blockDim.x + tid; t < total_tasks; t += stride) {
            int p = t >> 5;          // point index
            int f = t & 31;          // feature index

            float cx = coords[p * 3 + 0];
            float cy = coords[p * 3 + 1];
            float cz = coords[p * 3 + 2];

            // jnp.round = round-half-to-even; rintf matches (RNE default).
            int gx = (int)rintf(cx + MAX_DIST_F);
            int gy = (int)rintf(cy + MAX_DIST_F);
            int gz = (int)rintf(cz + MAX_DIST_F);

            bool in_box = (gx >= 0) & (gx < BOX) &
                          (gy >= 0) & (gy < BOX) &
                          (gz >= 0) & (gz < BOX);
            if (!in_box) continue;   // reference adds 0 at clamped index -> no-op

            float v = features[(size_t)p * NF + f];
            size_t idx = (((size_t)gx * BOX + gy) * BOX + gz) * NF + f;
            atomicAdd(grid + idx, v);
        }
    } else {
        // ---- zero blocks: the other 3/4 stream-zero slices 1..7 (320.7 MB) ----
        size_t zb = (size_t)(b >> 2) * 3 + (size_t)(b & 3) - 1;
        size_t nzb = ((size_t)gridDim.x >> 2) * 3;
        size_t stride = nzb * blockDim.x;
        vfloat4 z = {0.f, 0.f, 0.f, 0.f};
        for (size_t i = zb * blockDim.x + tid; i < rest_n4; i += stride)
            __builtin_nontemporal_store(z, &rest[i]);
    }
}

extern "C" void kernel_launch(void* const* d_in, const int* in_sizes, int n_in,
                              void* d_out, int out_size, void* d_ws, size_t ws_size,
                              hipStream_t stream) {
    const float* coords   = (const float*)d_in[0];  // [B,N,3] fp32
    const float* features = (const float*)d_in[1];  // [B,N,F] fp32
    float* out = (float*)d_out;                     // [B,71,71,71,F] fp32

    int total_points = in_sizes[0] / 3;             // B*N = 131072
    int total_tasks = total_points * NF;            // 4,194,304

    // Slice 0: 11,453,152 floats = 2,863,288 float4 (divisible by 4; 16B-aligned).
    int slice0_n4 = SLICE_FLOATS / 4;
    MakeGrid_zero_slice0<<<4096, 256, 0, stream>>>((vfloat4*)out, slice0_n4);

    // Slices 1..7: (out_size - SLICE_FLOATS) floats; base is 16B-aligned
    // (45,812,608 bytes = 16 * 2,863,288).
    size_t rest_n4 = ((size_t)out_size - SLICE_FLOATS) / 4;
    vfloat4* rest = (vfloat4*)(out + SLICE_FLOATS);

    MakeGrid_fused_scatter_zero<<<8192, 256, 0, stream>>>(
        coords, features, out, rest, rest_n4, total_tasks);
}